// Round 4
// baseline (1123.024 us; speedup 1.0000x reference)
//
#include <hip/hip_runtime.h>

// ICNN forward-of-gradient: out = 0.5*d(scalar)/dx + 0.5*x
// R4: uall GEMM + slim fwd (from R3) + UNFUSED bwd (R3 fusion regressed: 48KB LDS -> 13% occ).
//     bwd_g 24KB LDS; A1=2u*ga precomputed in producer epilogue; bwd_x K-split x4 + atomics.

#define Bn 8192
#define Dn 128
#define Hn 512
#define Ln 10
#define NW (Ln * Hn)   // 5120

constexpr float NS = 0.2f;

typedef __attribute__((ext_vector_type(8))) short short8;
typedef __attribute__((ext_vector_type(4))) float f32x4;

typedef const __attribute__((address_space(1))) void GV;
typedef __attribute__((address_space(3))) void LV;

__device__ __forceinline__ void gload16(const void* g, void* l) {
    __builtin_amdgcn_global_load_lds((GV*)g, (LV*)l, 16, 0, 0);
}

#define MFMA(acc, a, b) acc = __builtin_amdgcn_mfma_f32_16x16x32_bf16(a, b, acc, 0, 0, 0)

__device__ __forceinline__ unsigned short bf16_rne(float v) {
    unsigned u = __float_as_uint(v);
    u += 0x7FFFu + ((u >> 16) & 1u);
    return (unsigned short)(u >> 16);
}
__device__ __forceinline__ float bf2f(unsigned short h) {
    return __uint_as_float(((unsigned)h) << 16);
}
__device__ __forceinline__ void split2(float v, unsigned short& h, unsigned short& l) {
    h = bf16_rne(v);
    l = bf16_rne(v - bf2f(h));
}

// ---------------- prep kernels ----------------

__global__ __launch_bounds__(256) void split_flat(const float* __restrict__ in,
        unsigned short* __restrict__ hi, unsigned short* __restrict__ lo, int n4) {
    int i = blockIdx.x * 256 + threadIdx.x;
    if (i >= n4) return;
    float4 v = ((const float4*)in)[i];
    ushort4 h, l;
    split2(v.x, h.x, l.x);
    split2(v.y, h.y, l.y);
    split2(v.z, h.z, l.z);
    split2(v.w, h.w, l.w);
    ((ushort4*)hi)[i] = h;
    ((ushort4*)lo)[i] = l;
}

__global__ __launch_bounds__(256) void transpose_split(const float* __restrict__ in,
        unsigned short* __restrict__ hi, unsigned short* __restrict__ lo, int R, int C) {
    __shared__ float t[32][33];
    const size_t off = (size_t)blockIdx.z * R * C;
    const float* src = in + off;
    unsigned short* dh = hi + off;
    unsigned short* dl = lo + off;
    const int r0 = blockIdx.x * 32, c0 = blockIdx.y * 32;
    const int tr = threadIdx.x >> 5, tc = threadIdx.x & 31;
#pragma unroll
    for (int i = 0; i < 4; ++i)
        t[tr + 8 * i][tc] = src[(size_t)(r0 + tr + 8 * i) * C + c0 + tc];
    __syncthreads();
#pragma unroll
    for (int i = 0; i < 4; ++i) {
        float v = t[tc][tr + 8 * i];
        unsigned short h, l; split2(v, h, l);
        size_t o = (size_t)(c0 + tr + 8 * i) * R + r0 + tc;
        dh[o] = h; dl[o] = l;
    }
}

// ---------------- u_all = x @ WqAll^T : [8192 x 5120] fp32, 128x128 tiles ----------------

__global__ __launch_bounds__(256) void gemm_uall(
    const unsigned short* __restrict__ xh, const unsigned short* __restrict__ xl,
    const unsigned short* __restrict__ Wh, const unsigned short* __restrict__ Wv,
    float* __restrict__ u)
{
    __shared__ __align__(16) char smem[32768];
    unsigned short* Ah = (unsigned short*)smem;            // [128][32]
    unsigned short* Al = (unsigned short*)(smem + 8192);
    unsigned short* Bh = (unsigned short*)(smem + 16384);  // [128][32]
    unsigned short* Bl = (unsigned short*)(smem + 24576);

    const int tid = threadIdx.x;
    const int w = tid >> 6, lane = tid & 63;
    const int lq = lane >> 4, lc = lane & 15;
    const int wm = (w & 1) * 64, wn = (w >> 1) * 64;
    const int row0 = blockIdx.x * 128, col0 = blockIdx.y * 128;
    const int sr = lane >> 2, sk = (lane & 3) * 8;

    f32x4 acc[4][4];
#pragma unroll
    for (int i = 0; i < 4; ++i)
#pragma unroll
        for (int j = 0; j < 4; ++j)
#pragma unroll
            for (int r = 0; r < 4; ++r) acc[i][j][r] = 0.f;

    for (int k0 = 0; k0 < Dn; k0 += 32) {
        __syncthreads();
        for (int c = w; c < 8; c += 4) {
            size_t ga_ = (size_t)(row0 + c * 16 + sr) * Dn + k0 + sk;
            gload16(xh + ga_, Ah + c * 512);
            gload16(xl + ga_, Al + c * 512);
            size_t gb = (size_t)(col0 + c * 16 + sr) * Dn + k0 + sk;
            gload16(Wh + gb, Bh + c * 512);
            gload16(Wv + gb, Bl + c * 512);
        }
        __syncthreads();
        short8 ah[4], al[4];
#pragma unroll
        for (int mt = 0; mt < 4; ++mt) {
            int ao = (wm + mt * 16 + lc) * 32 + lq * 8;
            ah[mt] = *(const short8*)(Ah + ao);
            al[mt] = *(const short8*)(Al + ao);
        }
#pragma unroll
        for (int nt = 0; nt < 4; ++nt) {
            int bo = (wn + nt * 16 + lc) * 32 + lq * 8;
            short8 bh = *(const short8*)(Bh + bo);
            short8 bv = *(const short8*)(Bl + bo);
#pragma unroll
            for (int mt = 0; mt < 4; ++mt) {
                MFMA(acc[mt][nt], ah[mt], bh);
                MFMA(acc[mt][nt], ah[mt], bv);
                MFMA(acc[mt][nt], al[mt], bh);
            }
        }
    }

#pragma unroll
    for (int nt = 0; nt < 4; ++nt) {
        const int col = col0 + wn + nt * 16 + lc;
#pragma unroll
        for (int mt = 0; mt < 4; ++mt) {
            const int rowb = row0 + wm + mt * 16;
#pragma unroll
            for (int r = 0; r < 4; ++r)
                u[(size_t)(rowb + lq * 4 + r) * NW + col] = acc[mt][nt][r];
        }
    }
}

// ---------------- fwd layer: pre = zprev@Wz^T + u^2 + x@Wl^T + bl ----------------

__global__ __launch_bounds__(256) void fwd_mfma(
    const unsigned short* __restrict__ xh, const unsigned short* __restrict__ xl,
    const unsigned short* __restrict__ zph, const unsigned short* __restrict__ zpl,
    const unsigned short* __restrict__ Wzh, const unsigned short* __restrict__ Wzl,
    const unsigned short* __restrict__ Wlh, const unsigned short* __restrict__ Wll,
    const float* __restrict__ bl,
    const float* __restrict__ u,          // uall + l*Hn, ld = NW
    unsigned short* __restrict__ zoh, unsigned short* __restrict__ zol,
    unsigned short* __restrict__ mask16, int hasZ)
{
    __shared__ __align__(16) char smem[24576];
    unsigned short* Ah = (unsigned short*)smem;            // [128][32]
    unsigned short* Al = (unsigned short*)(smem + 8192);
    unsigned short* Bh = (unsigned short*)(smem + 16384);  // [64][32]
    unsigned short* Bl = (unsigned short*)(smem + 20480);

    const int tid = threadIdx.x;
    const int w = tid >> 6, lane = tid & 63;
    const int lq = lane >> 4, lc = lane & 15;
    const int wm = (w & 1) * 64, wn = (w >> 1) * 32;
    const int row0 = blockIdx.x * 128, col0 = blockIdx.y * 64;
    const int sr = lane >> 2, sk = (lane & 3) * 8;

    f32x4 acc[4][2];
#pragma unroll
    for (int i = 0; i < 4; ++i)
#pragma unroll
        for (int j = 0; j < 2; ++j)
#pragma unroll
            for (int r = 0; r < 4; ++r) acc[i][j][r] = 0.f;

    if (hasZ) {
        for (int k0 = 0; k0 < Hn; k0 += 32) {
            __syncthreads();
            for (int c = w; c < 8; c += 4) {
                size_t go = (size_t)(row0 + c * 16 + sr) * Hn + k0 + sk;
                gload16(zph + go, Ah + c * 512);
                gload16(zpl + go, Al + c * 512);
            }
            {
                int c = w;
                size_t go = (size_t)(col0 + c * 16 + sr) * Hn + k0 + sk;
                gload16(Wzh + go, Bh + c * 512);
                gload16(Wzl + go, Bl + c * 512);
            }
            __syncthreads();
            short8 ah[4], al[4];
#pragma unroll
            for (int mt = 0; mt < 4; ++mt) {
                int ao = (wm + mt * 16 + lc) * 32 + lq * 8;
                ah[mt] = *(const short8*)(Ah + ao);
                al[mt] = *(const short8*)(Al + ao);
            }
#pragma unroll
            for (int nt = 0; nt < 2; ++nt) {
                int bo = (wn + nt * 16 + lc) * 32 + lq * 8;
                short8 bh = *(const short8*)(Bh + bo);
                short8 bv = *(const short8*)(Bl + bo);
#pragma unroll
                for (int mt = 0; mt < 4; ++mt) {
                    MFMA(acc[mt][nt], ah[mt], bh);
                    MFMA(acc[mt][nt], ah[mt], bv);
                    MFMA(acc[mt][nt], al[mt], bh);
                }
            }
        }
    }

    for (int k0 = 0; k0 < Dn; k0 += 32) {
        __syncthreads();
        for (int c = w; c < 8; c += 4) {
            size_t go = (size_t)(row0 + c * 16 + sr) * Dn + k0 + sk;
            gload16(xh + go, Ah + c * 512);
            gload16(xl + go, Al + c * 512);
        }
        {
            int c = w;
            size_t go = (size_t)(col0 + c * 16 + sr) * Dn + k0 + sk;
            gload16(Wlh + go, Bh + c * 512);
            gload16(Wll + go, Bl + c * 512);
        }
        __syncthreads();
        short8 ah[4], al[4];
#pragma unroll
        for (int mt = 0; mt < 4; ++mt) {
            int ao = (wm + mt * 16 + lc) * 32 + lq * 8;
            ah[mt] = *(const short8*)(Ah + ao);
            al[mt] = *(const short8*)(Al + ao);
        }
#pragma unroll
        for (int nt = 0; nt < 2; ++nt) {
            int bo = (wn + nt * 16 + lc) * 32 + lq * 8;
            short8 bh = *(const short8*)(Bh + bo);
            short8 bv = *(const short8*)(Bl + bo);
#pragma unroll
            for (int mt = 0; mt < 4; ++mt) {
                MFMA(acc[mt][nt], ah[mt], bh);
                MFMA(acc[mt][nt], ah[mt], bv);
                MFMA(acc[mt][nt], al[mt], bh);
            }
        }
    }

#pragma unroll
    for (int nt = 0; nt < 2; ++nt) {
        const int colb = col0 + wn + nt * 16;
        const int col = colb + lc;
        const float blv = bl[col];
#pragma unroll
        for (int mt = 0; mt < 4; ++mt) {
            const int rowb = row0 + wm + mt * 16;
#pragma unroll
            for (int r = 0; r < 4; ++r) {
                const int row = rowb + lq * 4 + r;
                float uq = u[(size_t)row * NW + col];
                float pre = acc[mt][nt][r] + uq * uq + blv;
                bool m = pre >= 0.f;
                unsigned long long bal = __ballot(m);
                if (lc == 0) {
                    mask16[(size_t)row * 32 + (colb >> 4)] =
                        (unsigned short)((bal >> (lq * 16)) & 0xFFFFull);
                }
                float zv = m ? pre : NS * pre;
                unsigned short h, l; split2(zv, h, l);
                size_t o = (size_t)row * Hn + col;
                zoh[o] = h; zol[o] = l;
            }
        }
    }
}

// ---------------- ga_{l-1} = (ga_l @ Wz) o mask' ; epilogue also writes A1_{l-1} ----------------

__global__ __launch_bounds__(256) void bwd_g_mfma(
    const unsigned short* __restrict__ gah, const unsigned short* __restrict__ gal,
    const unsigned short* __restrict__ WzTh, const unsigned short* __restrict__ WzTl,
    const unsigned short* __restrict__ maskprev,
    const float* __restrict__ u,          // uall + (l-1)*Hn, ld = NW
    unsigned short* __restrict__ goh, unsigned short* __restrict__ gol,
    unsigned short* __restrict__ a1h, unsigned short* __restrict__ a1l)
{
    __shared__ __align__(16) char smem[24576];
    unsigned short* Ah = (unsigned short*)smem;
    unsigned short* Al = (unsigned short*)(smem + 8192);
    unsigned short* Bh = (unsigned short*)(smem + 16384);
    unsigned short* Bl = (unsigned short*)(smem + 20480);

    const int tid = threadIdx.x;
    const int w = tid >> 6, lane = tid & 63;
    const int lq = lane >> 4, lc = lane & 15;
    const int wm = (w & 1) * 64, wn = (w >> 1) * 32;
    const int row0 = blockIdx.x * 128, col0 = blockIdx.y * 64;
    const int sr = lane >> 2, sk = (lane & 3) * 8;

    f32x4 acc[4][2];
#pragma unroll
    for (int i = 0; i < 4; ++i)
#pragma unroll
        for (int j = 0; j < 2; ++j)
#pragma unroll
            for (int r = 0; r < 4; ++r) acc[i][j][r] = 0.f;

    for (int k0 = 0; k0 < Hn; k0 += 32) {
        __syncthreads();
        for (int c = w; c < 8; c += 4) {
            size_t go = (size_t)(row0 + c * 16 + sr) * Hn + k0 + sk;
            gload16(gah + go, Ah + c * 512);
            gload16(gal + go, Al + c * 512);
        }
        {
            int c = w;
            size_t go = (size_t)(col0 + c * 16 + sr) * Hn + k0 + sk;
            gload16(WzTh + go, Bh + c * 512);
            gload16(WzTl + go, Bl + c * 512);
        }
        __syncthreads();
        short8 ah[4], al[4];
#pragma unroll
        for (int mt = 0; mt < 4; ++mt) {
            int ao = (wm + mt * 16 + lc) * 32 + lq * 8;
            ah[mt] = *(const short8*)(Ah + ao);
            al[mt] = *(const short8*)(Al + ao);
        }
#pragma unroll
        for (int nt = 0; nt < 2; ++nt) {
            int bo = (wn + nt * 16 + lc) * 32 + lq * 8;
            short8 bh = *(const short8*)(Bh + bo);
            short8 bv = *(const short8*)(Bl + bo);
#pragma unroll
            for (int mt = 0; mt < 4; ++mt) {
                MFMA(acc[mt][nt], ah[mt], bh);
                MFMA(acc[mt][nt], ah[mt], bv);
                MFMA(acc[mt][nt], al[mt], bh);
            }
        }
    }

#pragma unroll
    for (int nt = 0; nt < 2; ++nt) {
        const int colb = col0 + wn + nt * 16;
        const int col = colb + lc;
#pragma unroll
        for (int mt = 0; mt < 4; ++mt) {
            const int rowb = row0 + wm + mt * 16;
#pragma unroll
            for (int r = 0; r < 4; ++r) {
                int row = rowb + lq * 4 + r;
                unsigned short wbits = maskprev[(size_t)row * 32 + (colb >> 4)];
                float f = ((wbits >> lc) & 1) ? 1.f : NS;
                float v = acc[mt][nt][r] * f;
                unsigned short h, l; split2(v, h, l);
                size_t o = (size_t)row * Hn + col;
                goh[o] = h; gol[o] = l;
                float uv = u[(size_t)row * NW + col];
                float a1 = 2.f * uv * v;
                split2(a1, h, l);
                a1h[o] = h; a1l[o] = l;
            }
        }
    }
}

// ---------------- gx(atomic) += A1@WqT + A2@WlT ; 64x64 tile, K-chunked ----------------

__global__ __launch_bounds__(256) void bwd_x_mfma(
    const unsigned short* __restrict__ a1h, const unsigned short* __restrict__ a1l,
    const unsigned short* __restrict__ a2h, const unsigned short* __restrict__ a2l,
    const unsigned short* __restrict__ WqTh, const unsigned short* __restrict__ WqTl,
    const unsigned short* __restrict__ WlTh, const unsigned short* __restrict__ WlTl,
    float* __restrict__ gx)
{
    __shared__ __align__(16) char smem[32768];
    unsigned short* A1h = (unsigned short*)smem;            // [64][32] each
    unsigned short* A1l = (unsigned short*)(smem + 4096);
    unsigned short* A2h = (unsigned short*)(smem + 8192);
    unsigned short* A2l = (unsigned short*)(smem + 12288);
    unsigned short* Bqh = (unsigned short*)(smem + 16384);
    unsigned short* Bql = (unsigned short*)(smem + 20480);
    unsigned short* Blh = (unsigned short*)(smem + 24576);
    unsigned short* Bll = (unsigned short*)(smem + 28672);

    const int tid = threadIdx.x;
    const int w = tid >> 6, lane = tid & 63;
    const int lq = lane >> 4, lc = lane & 15;
    const int wm = (w & 1) * 32, wn = (w >> 1) * 32;
    const int row0 = blockIdx.x * 64, col0 = blockIdx.y * 64;
    const int kb = blockIdx.z * 128;
    const int str = tid >> 2, stk = (tid & 3) * 8;   // staging: row 0..63, k-off

    f32x4 acc[2][2];
#pragma unroll
    for (int i = 0; i < 2; ++i)
#pragma unroll
        for (int j = 0; j < 2; ++j)
#pragma unroll
            for (int r = 0; r < 4; ++r) acc[i][j][r] = 0.f;

    for (int k0 = kb; k0 < kb + 128; k0 += 32) {
        __syncthreads();
        {
            size_t ga_ = (size_t)(row0 + str) * Hn + k0 + stk;
            size_t gb = (size_t)(col0 + str) * Hn + k0 + stk;
            int lo_ = str * 32 + stk;
            gload16(a1h + ga_, A1h + lo_);
            gload16(a1l + ga_, A1l + lo_);
            gload16(a2h + ga_, A2h + lo_);
            gload16(a2l + ga_, A2l + lo_);
            gload16(WqTh + gb, Bqh + lo_);
            gload16(WqTl + gb, Bql + lo_);
            gload16(WlTh + gb, Blh + lo_);
            gload16(WlTl + gb, Bll + lo_);
        }
        __syncthreads();
        short8 f1h[2], f1l[2], f2h[2], f2l[2];
#pragma unroll
        for (int mt = 0; mt < 2; ++mt) {
            int ao = (wm + mt * 16 + lc) * 32 + lq * 8;
            f1h[mt] = *(const short8*)(A1h + ao);
            f1l[mt] = *(const short8*)(A1l + ao);
            f2h[mt] = *(const short8*)(A2h + ao);
            f2l[mt] = *(const short8*)(A2l + ao);
        }
#pragma unroll
        for (int nt = 0; nt < 2; ++nt) {
            int bo = (wn + nt * 16 + lc) * 32 + lq * 8;
            short8 qh = *(const short8*)(Bqh + bo);
            short8 ql_ = *(const short8*)(Bql + bo);
            short8 lh = *(const short8*)(Blh + bo);
            short8 ll_ = *(const short8*)(Bll + bo);
#pragma unroll
            for (int mt = 0; mt < 2; ++mt) {
                MFMA(acc[mt][nt], f1h[mt], qh);
                MFMA(acc[mt][nt], f1h[mt], ql_);
                MFMA(acc[mt][nt], f1l[mt], qh);
                MFMA(acc[mt][nt], f2h[mt], lh);
                MFMA(acc[mt][nt], f2h[mt], ll_);
                MFMA(acc[mt][nt], f2l[mt], lh);
            }
        }
    }

#pragma unroll
    for (int nt = 0; nt < 2; ++nt) {
        const int col = col0 + wn + nt * 16 + lc;
#pragma unroll
        for (int mt = 0; mt < 2; ++mt) {
            const int rowb = row0 + wm + mt * 16;
#pragma unroll
            for (int r = 0; r < 4; ++r)
                atomicAdd(&gx[(size_t)(rowb + lq * 4 + r) * Dn + col], acc[mt][nt][r]);
        }
    }
}

// ---------------- small kernels ----------------

__global__ __launch_bounds__(256) void zero_out(float* __restrict__ p, int n4) {
    int i = blockIdx.x * 256 + threadIdx.x;
    if (i < n4) ((float4*)p)[i] = make_float4(0.f, 0.f, 0.f, 0.f);
}

__global__ __launch_bounds__(256) void ga_init(
    const float* __restrict__ wz_out, const unsigned short* __restrict__ mask9,
    const float* __restrict__ u9,     // uall + 9*Hn, ld NW
    unsigned short* __restrict__ gh, unsigned short* __restrict__ gl,
    unsigned short* __restrict__ a1h, unsigned short* __restrict__ a1l)
{
    int i = blockIdx.x * 256 + threadIdx.x;
    int e = i << 2;
    int b = e >> 9, h = e & 511;
    unsigned short wbits = mask9[(size_t)b * 32 + (h >> 4)];
    float4 wv = *(const float4*)(wz_out + h);
    float4 uv = *(const float4*)(u9 + (size_t)b * NW + h);
    int sh = h & 15;
    ushort4 oh, ol, th, tl;
    float f;
    f = wv.x * (((wbits >> (sh + 0)) & 1) ? 1.f : NS); split2(f, oh.x, ol.x); split2(2.f * uv.x * f, th.x, tl.x);
    f = wv.y * (((wbits >> (sh + 1)) & 1) ? 1.f : NS); split2(f, oh.y, ol.y); split2(2.f * uv.y * f, th.y, tl.y);
    f = wv.z * (((wbits >> (sh + 2)) & 1) ? 1.f : NS); split2(f, oh.z, ol.z); split2(2.f * uv.z * f, th.z, tl.z);
    f = wv.w * (((wbits >> (sh + 3)) & 1) ? 1.f : NS); split2(f, oh.w, ol.w); split2(2.f * uv.w * f, th.w, tl.w);
    *(ushort4*)(gh + e) = oh;
    *(ushort4*)(gl + e) = ol;
    *(ushort4*)(a1h + e) = th;
    *(ushort4*)(a1l + e) = tl;
}

__global__ __launch_bounds__(256) void rowdot_kernel(
    const float* __restrict__ x, const float* __restrict__ wq_out, float* __restrict__ s) {
    const int b = blockIdx.x * 4 + (threadIdx.x >> 6);
    const int lane = threadIdx.x & 63;
    float v = x[(size_t)b * Dn + lane] * wq_out[lane] +
              x[(size_t)b * Dn + 64 + lane] * wq_out[64 + lane];
#pragma unroll
    for (int off = 32; off > 0; off >>= 1) v += __shfl_down(v, off, 64);
    if (lane == 0) s[b] = v;
}

__global__ __launch_bounds__(256) void final_kernel(
    float* __restrict__ out, const float* __restrict__ x, const float* __restrict__ s,
    const float* __restrict__ wq_out, const float* __restrict__ wl_out) {
    const int i = blockIdx.x * 256 + threadIdx.x;
    const int base = i << 2;
    const int b = base >> 7;
    const int d = base & (Dn - 1);
    float4 g = *(const float4*)(out + base);
    float4 xv = *(const float4*)(x + base);
    float4 wq = *(const float4*)(wq_out + d);
    float4 wl = *(const float4*)(wl_out + d);
    const float sb = s[b];
    float4 o;
    o.x = 0.5f * g.x + sb * wq.x + 0.5f * wl.x + 0.5f * xv.x;
    o.y = 0.5f * g.y + sb * wq.y + 0.5f * wl.y + 0.5f * xv.y;
    o.z = 0.5f * g.z + sb * wq.z + 0.5f * wl.z + 0.5f * xv.z;
    o.w = 0.5f * g.w + sb * wq.w + 0.5f * wl.w + 0.5f * xv.w;
    *(float4*)(out + base) = o;
}

// ---------------- launcher ----------------

extern "C" void kernel_launch(void* const* d_in, const int* in_sizes, int n_in,
                              void* d_out, int out_size, void* d_ws, size_t ws_size,
                              hipStream_t stream) {
    (void)in_sizes; (void)n_in; (void)out_size; (void)ws_size;
    const float* x      = (const float*)d_in[0];
    const float* Wq     = (const float*)d_in[1];
    const float* Wl     = (const float*)d_in[2];
    const float* bl     = (const float*)d_in[3];
    const float* Wz     = (const float*)d_in[4];
    const float* wz_out = (const float*)d_in[5];
    const float* wq_out = (const float*)d_in[6];
    const float* wl_out = (const float*)d_in[7];
    float* out = (float*)d_out;

    char* p = (char*)d_ws;
    #define CARVE(name, bytes) unsigned short* name = (unsigned short*)p; p += (((size_t)(bytes)) + 255) & ~(size_t)255;
    CARVE(xh,  (size_t)Bn*Dn*2)  CARVE(xl,  (size_t)Bn*Dn*2)
    CARVE(Wqh, (size_t)Ln*Hn*Dn*2) CARVE(Wql, (size_t)Ln*Hn*Dn*2)
    CARVE(Wlh, (size_t)Ln*Hn*Dn*2) CARVE(Wll, (size_t)Ln*Hn*Dn*2)
    CARVE(WqTh,(size_t)Ln*Hn*Dn*2) CARVE(WqTl,(size_t)Ln*Hn*Dn*2)
    CARVE(WlTh,(size_t)Ln*Hn*Dn*2) CARVE(WlTl,(size_t)Ln*Hn*Dn*2)
    CARVE(Wzh, (size_t)(Ln-1)*Hn*Hn*2) CARVE(Wzl, (size_t)(Ln-1)*Hn*Hn*2)
    CARVE(WzTh,(size_t)(Ln-1)*Hn*Hn*2) CARVE(WzTl,(size_t)(Ln-1)*Hn*Hn*2)
    CARVE(zAh, (size_t)Bn*Hn*2) CARVE(zAl, (size_t)Bn*Hn*2)
    CARVE(zBh, (size_t)Bn*Hn*2) CARVE(zBl, (size_t)Bn*Hn*2)
    CARVE(a1h, (size_t)Bn*Hn*2) CARVE(a1l, (size_t)Bn*Hn*2)
    CARVE(mask16, (size_t)Ln*Bn*32*2)
    float* s = (float*)p; p += (size_t)Bn*4 + 256;
    float* uall = (float*)p; p += (size_t)Bn*NW*4;   // 167.8 MB; total ~257 MB < 268 MB
    #undef CARVE

    split_flat<<<(Bn*Dn/4 + 255)/256, 256, 0, stream>>>(x, xh, xl, Bn*Dn/4);
    split_flat<<<(Ln*Hn*Dn/4 + 255)/256, 256, 0, stream>>>(Wq, Wqh, Wql, Ln*Hn*Dn/4);
    split_flat<<<(Ln*Hn*Dn/4 + 255)/256, 256, 0, stream>>>(Wl, Wlh, Wll, Ln*Hn*Dn/4);
    split_flat<<<((Ln-1)*Hn*Hn/4 + 255)/256, 256, 0, stream>>>(Wz, Wzh, Wzl, (Ln-1)*Hn*Hn/4);
    transpose_split<<<dim3(Hn/32, Dn/32, Ln), 256, 0, stream>>>(Wq, WqTh, WqTl, Hn, Dn);
    transpose_split<<<dim3(Hn/32, Dn/32, Ln), 256, 0, stream>>>(Wl, WlTh, WlTl, Hn, Dn);
    transpose_split<<<dim3(Hn/32, Hn/32, Ln-1), 256, 0, stream>>>(Wz, WzTh, WzTl, Hn, Hn);

    rowdot_kernel<<<Bn/4, 256, 0, stream>>>(x, wq_out, s);

    gemm_uall<<<dim3(Bn/128, NW/128), 256, 0, stream>>>(xh, xl, Wqh, Wql, uall);

    const dim3 gF(Bn/128, Hn/64);  // 64 x 8

    fwd_mfma<<<gF, 256, 0, stream>>>(xh, xl, nullptr, nullptr, nullptr, nullptr,
        Wlh, Wll, bl, uall, zAh, zAl, mask16, 0);
    for (int l = 1; l < Ln; ++l) {
        const unsigned short* zh  = (l & 1) ? zAh : zBh;
        const unsigned short* zl_ = (l & 1) ? zAl : zBl;
        unsigned short* oh  = (l & 1) ? zBh : zAh;
        unsigned short* ol_ = (l & 1) ? zBl : zAl;
        fwd_mfma<<<gF, 256, 0, stream>>>(xh, xl, zh, zl_,
            Wzh + (size_t)(l-1)*Hn*Hn, Wzl + (size_t)(l-1)*Hn*Hn,
            Wlh + (size_t)l*Hn*Dn, Wll + (size_t)l*Hn*Dn,
            bl + (size_t)l*Hn, uall + (size_t)l*Hn,
            oh, ol_, mask16 + (size_t)l*Bn*32, 1);
    }

    zero_out<<<(Bn*Dn/4 + 255)/256, 256, 0, stream>>>(out, Bn*Dn/4);
    ga_init<<<(Bn*Hn/4)/256, 256, 0, stream>>>(wz_out, mask16 + (size_t)9*Bn*32,
        uall + (size_t)9*Hn, zAh, zAl, a1h, a1l);

    for (int l = Ln - 1; l >= 0; --l) {
        int sidx = (Ln - 1 - l) & 1;
        const unsigned short* gh_ = sidx ? zBh : zAh;
        const unsigned short* gl_ = sidx ? zBl : zAl;
        // gx partial for layer l (atomic accumulate), K split x4 -> 1024 blocks
        bwd_x_mfma<<<dim3(Bn/64, Dn/64, 4), 256, 0, stream>>>(
            a1h, a1l, gh_, gl_,
            WqTh + (size_t)l*Dn*Hn, WqTl + (size_t)l*Dn*Hn,
            WlTh + (size_t)l*Dn*Hn, WlTl + (size_t)l*Dn*Hn, out);
        if (l > 0) {
            unsigned short* oh  = sidx ? zAh : zBh;
            unsigned short* ol_ = sidx ? zAl : zBl;
            bwd_g_mfma<<<gF, 256, 0, stream>>>(gh_, gl_,
                WzTh + (size_t)(l-1)*Hn*Hn, WzTl + (size_t)(l-1)*Hn*Hn,
                mask16 + (size_t)(l-1)*Bn*32,
                uall + (size_t)(l-1)*Hn,
                oh, ol_, a1h, a1l);
        }
    }

    final_kernel<<<(Bn*Dn/4)/256, 256, 0, stream>>>(out, x, s, wq_out, wl_out);
}

// Round 5
// 1048.590 us; speedup vs baseline: 1.0710x; 1.0710x over previous
//
#include <hip/hip_runtime.h>

// ICNN forward-of-gradient: out = 0.5*d(scalar)/dx + 0.5*x
// R5: R4 minus atomics. bwd_x accumulates into 2 private fp32 gx slabs (blockIdx.z-owned,
//     RMW across serialized layer launches); final sums slabs. Atomics were the R4 regression
//     (40ms pathological dispatch under rocprof; ~44us/launch in graph mode).

#define Bn 8192
#define Dn 128
#define Hn 512
#define Ln 10
#define NW (Ln * Hn)   // 5120

constexpr float NS = 0.2f;

typedef __attribute__((ext_vector_type(8))) short short8;
typedef __attribute__((ext_vector_type(4))) float f32x4;

typedef const __attribute__((address_space(1))) void GV;
typedef __attribute__((address_space(3))) void LV;

__device__ __forceinline__ void gload16(const void* g, void* l) {
    __builtin_amdgcn_global_load_lds((GV*)g, (LV*)l, 16, 0, 0);
}

#define MFMA(acc, a, b) acc = __builtin_amdgcn_mfma_f32_16x16x32_bf16(a, b, acc, 0, 0, 0)

__device__ __forceinline__ unsigned short bf16_rne(float v) {
    unsigned u = __float_as_uint(v);
    u += 0x7FFFu + ((u >> 16) & 1u);
    return (unsigned short)(u >> 16);
}
__device__ __forceinline__ float bf2f(unsigned short h) {
    return __uint_as_float(((unsigned)h) << 16);
}
__device__ __forceinline__ void split2(float v, unsigned short& h, unsigned short& l) {
    h = bf16_rne(v);
    l = bf16_rne(v - bf2f(h));
}

// ---------------- prep kernels ----------------

__global__ __launch_bounds__(256) void split_flat(const float* __restrict__ in,
        unsigned short* __restrict__ hi, unsigned short* __restrict__ lo, int n4) {
    int i = blockIdx.x * 256 + threadIdx.x;
    if (i >= n4) return;
    float4 v = ((const float4*)in)[i];
    ushort4 h, l;
    split2(v.x, h.x, l.x);
    split2(v.y, h.y, l.y);
    split2(v.z, h.z, l.z);
    split2(v.w, h.w, l.w);
    ((ushort4*)hi)[i] = h;
    ((ushort4*)lo)[i] = l;
}

__global__ __launch_bounds__(256) void transpose_split(const float* __restrict__ in,
        unsigned short* __restrict__ hi, unsigned short* __restrict__ lo, int R, int C) {
    __shared__ float t[32][33];
    const size_t off = (size_t)blockIdx.z * R * C;
    const float* src = in + off;
    unsigned short* dh = hi + off;
    unsigned short* dl = lo + off;
    const int r0 = blockIdx.x * 32, c0 = blockIdx.y * 32;
    const int tr = threadIdx.x >> 5, tc = threadIdx.x & 31;
#pragma unroll
    for (int i = 0; i < 4; ++i)
        t[tr + 8 * i][tc] = src[(size_t)(r0 + tr + 8 * i) * C + c0 + tc];
    __syncthreads();
#pragma unroll
    for (int i = 0; i < 4; ++i) {
        float v = t[tc][tr + 8 * i];
        unsigned short h, l; split2(v, h, l);
        size_t o = (size_t)(c0 + tr + 8 * i) * R + r0 + tc;
        dh[o] = h; dl[o] = l;
    }
}

// ---------------- u_all = x @ WqAll^T : [8192 x 5120] fp32, 128x128 tiles ----------------

__global__ __launch_bounds__(256) void gemm_uall(
    const unsigned short* __restrict__ xh, const unsigned short* __restrict__ xl,
    const unsigned short* __restrict__ Wh, const unsigned short* __restrict__ Wv,
    float* __restrict__ u)
{
    __shared__ __align__(16) char smem[32768];
    unsigned short* Ah = (unsigned short*)smem;            // [128][32]
    unsigned short* Al = (unsigned short*)(smem + 8192);
    unsigned short* Bh = (unsigned short*)(smem + 16384);  // [128][32]
    unsigned short* Bl = (unsigned short*)(smem + 24576);

    const int tid = threadIdx.x;
    const int w = tid >> 6, lane = tid & 63;
    const int lq = lane >> 4, lc = lane & 15;
    const int wm = (w & 1) * 64, wn = (w >> 1) * 64;
    const int row0 = blockIdx.x * 128, col0 = blockIdx.y * 128;
    const int sr = lane >> 2, sk = (lane & 3) * 8;

    f32x4 acc[4][4];
#pragma unroll
    for (int i = 0; i < 4; ++i)
#pragma unroll
        for (int j = 0; j < 4; ++j)
#pragma unroll
            for (int r = 0; r < 4; ++r) acc[i][j][r] = 0.f;

    for (int k0 = 0; k0 < Dn; k0 += 32) {
        __syncthreads();
        for (int c = w; c < 8; c += 4) {
            size_t ga_ = (size_t)(row0 + c * 16 + sr) * Dn + k0 + sk;
            gload16(xh + ga_, Ah + c * 512);
            gload16(xl + ga_, Al + c * 512);
            size_t gb = (size_t)(col0 + c * 16 + sr) * Dn + k0 + sk;
            gload16(Wh + gb, Bh + c * 512);
            gload16(Wv + gb, Bl + c * 512);
        }
        __syncthreads();
        short8 ah[4], al[4];
#pragma unroll
        for (int mt = 0; mt < 4; ++mt) {
            int ao = (wm + mt * 16 + lc) * 32 + lq * 8;
            ah[mt] = *(const short8*)(Ah + ao);
            al[mt] = *(const short8*)(Al + ao);
        }
#pragma unroll
        for (int nt = 0; nt < 4; ++nt) {
            int bo = (wn + nt * 16 + lc) * 32 + lq * 8;
            short8 bh = *(const short8*)(Bh + bo);
            short8 bv = *(const short8*)(Bl + bo);
#pragma unroll
            for (int mt = 0; mt < 4; ++mt) {
                MFMA(acc[mt][nt], ah[mt], bh);
                MFMA(acc[mt][nt], ah[mt], bv);
                MFMA(acc[mt][nt], al[mt], bh);
            }
        }
    }

#pragma unroll
    for (int nt = 0; nt < 4; ++nt) {
        const int col = col0 + wn + nt * 16 + lc;
#pragma unroll
        for (int mt = 0; mt < 4; ++mt) {
            const int rowb = row0 + wm + mt * 16;
#pragma unroll
            for (int r = 0; r < 4; ++r)
                u[(size_t)(rowb + lq * 4 + r) * NW + col] = acc[mt][nt][r];
        }
    }
}

// ---------------- fwd layer: pre = zprev@Wz^T + u^2 + x@Wl^T + bl ----------------

__global__ __launch_bounds__(256) void fwd_mfma(
    const unsigned short* __restrict__ xh, const unsigned short* __restrict__ xl,
    const unsigned short* __restrict__ zph, const unsigned short* __restrict__ zpl,
    const unsigned short* __restrict__ Wzh, const unsigned short* __restrict__ Wzl,
    const unsigned short* __restrict__ Wlh, const unsigned short* __restrict__ Wll,
    const float* __restrict__ bl,
    const float* __restrict__ u,          // uall + l*Hn, ld = NW
    unsigned short* __restrict__ zoh, unsigned short* __restrict__ zol,
    unsigned short* __restrict__ mask16, int hasZ)
{
    __shared__ __align__(16) char smem[24576];
    unsigned short* Ah = (unsigned short*)smem;            // [128][32]
    unsigned short* Al = (unsigned short*)(smem + 8192);
    unsigned short* Bh = (unsigned short*)(smem + 16384);  // [64][32]
    unsigned short* Bl = (unsigned short*)(smem + 20480);

    const int tid = threadIdx.x;
    const int w = tid >> 6, lane = tid & 63;
    const int lq = lane >> 4, lc = lane & 15;
    const int wm = (w & 1) * 64, wn = (w >> 1) * 32;
    const int row0 = blockIdx.x * 128, col0 = blockIdx.y * 64;
    const int sr = lane >> 2, sk = (lane & 3) * 8;

    f32x4 acc[4][2];
#pragma unroll
    for (int i = 0; i < 4; ++i)
#pragma unroll
        for (int j = 0; j < 2; ++j)
#pragma unroll
            for (int r = 0; r < 4; ++r) acc[i][j][r] = 0.f;

    if (hasZ) {
        for (int k0 = 0; k0 < Hn; k0 += 32) {
            __syncthreads();
            for (int c = w; c < 8; c += 4) {
                size_t go = (size_t)(row0 + c * 16 + sr) * Hn + k0 + sk;
                gload16(zph + go, Ah + c * 512);
                gload16(zpl + go, Al + c * 512);
            }
            {
                int c = w;
                size_t go = (size_t)(col0 + c * 16 + sr) * Hn + k0 + sk;
                gload16(Wzh + go, Bh + c * 512);
                gload16(Wzl + go, Bl + c * 512);
            }
            __syncthreads();
            short8 ah[4], al[4];
#pragma unroll
            for (int mt = 0; mt < 4; ++mt) {
                int ao = (wm + mt * 16 + lc) * 32 + lq * 8;
                ah[mt] = *(const short8*)(Ah + ao);
                al[mt] = *(const short8*)(Al + ao);
            }
#pragma unroll
            for (int nt = 0; nt < 2; ++nt) {
                int bo = (wn + nt * 16 + lc) * 32 + lq * 8;
                short8 bh = *(const short8*)(Bh + bo);
                short8 bv = *(const short8*)(Bl + bo);
#pragma unroll
                for (int mt = 0; mt < 4; ++mt) {
                    MFMA(acc[mt][nt], ah[mt], bh);
                    MFMA(acc[mt][nt], ah[mt], bv);
                    MFMA(acc[mt][nt], al[mt], bh);
                }
            }
        }
    }

    for (int k0 = 0; k0 < Dn; k0 += 32) {
        __syncthreads();
        for (int c = w; c < 8; c += 4) {
            size_t go = (size_t)(row0 + c * 16 + sr) * Dn + k0 + sk;
            gload16(xh + go, Ah + c * 512);
            gload16(xl + go, Al + c * 512);
        }
        {
            int c = w;
            size_t go = (size_t)(col0 + c * 16 + sr) * Dn + k0 + sk;
            gload16(Wlh + go, Bh + c * 512);
            gload16(Wll + go, Bl + c * 512);
        }
        __syncthreads();
        short8 ah[4], al[4];
#pragma unroll
        for (int mt = 0; mt < 4; ++mt) {
            int ao = (wm + mt * 16 + lc) * 32 + lq * 8;
            ah[mt] = *(const short8*)(Ah + ao);
            al[mt] = *(const short8*)(Al + ao);
        }
#pragma unroll
        for (int nt = 0; nt < 2; ++nt) {
            int bo = (wn + nt * 16 + lc) * 32 + lq * 8;
            short8 bh = *(const short8*)(Bh + bo);
            short8 bv = *(const short8*)(Bl + bo);
#pragma unroll
            for (int mt = 0; mt < 4; ++mt) {
                MFMA(acc[mt][nt], ah[mt], bh);
                MFMA(acc[mt][nt], ah[mt], bv);
                MFMA(acc[mt][nt], al[mt], bh);
            }
        }
    }

#pragma unroll
    for (int nt = 0; nt < 2; ++nt) {
        const int colb = col0 + wn + nt * 16;
        const int col = colb + lc;
        const float blv = bl[col];
#pragma unroll
        for (int mt = 0; mt < 4; ++mt) {
            const int rowb = row0 + wm + mt * 16;
#pragma unroll
            for (int r = 0; r < 4; ++r) {
                const int row = rowb + lq * 4 + r;
                float uq = u[(size_t)row * NW + col];
                float pre = acc[mt][nt][r] + uq * uq + blv;
                bool m = pre >= 0.f;
                unsigned long long bal = __ballot(m);
                if (lc == 0) {
                    mask16[(size_t)row * 32 + (colb >> 4)] =
                        (unsigned short)((bal >> (lq * 16)) & 0xFFFFull);
                }
                float zv = m ? pre : NS * pre;
                unsigned short h, l; split2(zv, h, l);
                size_t o = (size_t)row * Hn + col;
                zoh[o] = h; zol[o] = l;
            }
        }
    }
}

// ---------------- ga_{l-1} = (ga_l @ Wz) o mask' ; epilogue also writes A1_{l-1} ----------------

__global__ __launch_bounds__(256) void bwd_g_mfma(
    const unsigned short* __restrict__ gah, const unsigned short* __restrict__ gal,
    const unsigned short* __restrict__ WzTh, const unsigned short* __restrict__ WzTl,
    const unsigned short* __restrict__ maskprev,
    const float* __restrict__ u,          // uall + (l-1)*Hn, ld = NW
    unsigned short* __restrict__ goh, unsigned short* __restrict__ gol,
    unsigned short* __restrict__ a1h, unsigned short* __restrict__ a1l)
{
    __shared__ __align__(16) char smem[24576];
    unsigned short* Ah = (unsigned short*)smem;
    unsigned short* Al = (unsigned short*)(smem + 8192);
    unsigned short* Bh = (unsigned short*)(smem + 16384);
    unsigned short* Bl = (unsigned short*)(smem + 20480);

    const int tid = threadIdx.x;
    const int w = tid >> 6, lane = tid & 63;
    const int lq = lane >> 4, lc = lane & 15;
    const int wm = (w & 1) * 64, wn = (w >> 1) * 32;
    const int row0 = blockIdx.x * 128, col0 = blockIdx.y * 64;
    const int sr = lane >> 2, sk = (lane & 3) * 8;

    f32x4 acc[4][2];
#pragma unroll
    for (int i = 0; i < 4; ++i)
#pragma unroll
        for (int j = 0; j < 2; ++j)
#pragma unroll
            for (int r = 0; r < 4; ++r) acc[i][j][r] = 0.f;

    for (int k0 = 0; k0 < Hn; k0 += 32) {
        __syncthreads();
        for (int c = w; c < 8; c += 4) {
            size_t go = (size_t)(row0 + c * 16 + sr) * Hn + k0 + sk;
            gload16(gah + go, Ah + c * 512);
            gload16(gal + go, Al + c * 512);
        }
        {
            int c = w;
            size_t go = (size_t)(col0 + c * 16 + sr) * Hn + k0 + sk;
            gload16(WzTh + go, Bh + c * 512);
            gload16(WzTl + go, Bl + c * 512);
        }
        __syncthreads();
        short8 ah[4], al[4];
#pragma unroll
        for (int mt = 0; mt < 4; ++mt) {
            int ao = (wm + mt * 16 + lc) * 32 + lq * 8;
            ah[mt] = *(const short8*)(Ah + ao);
            al[mt] = *(const short8*)(Al + ao);
        }
#pragma unroll
        for (int nt = 0; nt < 2; ++nt) {
            int bo = (wn + nt * 16 + lc) * 32 + lq * 8;
            short8 bh = *(const short8*)(Bh + bo);
            short8 bv = *(const short8*)(Bl + bo);
#pragma unroll
            for (int mt = 0; mt < 4; ++mt) {
                MFMA(acc[mt][nt], ah[mt], bh);
                MFMA(acc[mt][nt], ah[mt], bv);
                MFMA(acc[mt][nt], al[mt], bh);
            }
        }
    }

#pragma unroll
    for (int nt = 0; nt < 2; ++nt) {
        const int colb = col0 + wn + nt * 16;
        const int col = colb + lc;
#pragma unroll
        for (int mt = 0; mt < 4; ++mt) {
            const int rowb = row0 + wm + mt * 16;
#pragma unroll
            for (int r = 0; r < 4; ++r) {
                int row = rowb + lq * 4 + r;
                unsigned short wbits = maskprev[(size_t)row * 32 + (colb >> 4)];
                float f = ((wbits >> lc) & 1) ? 1.f : NS;
                float v = acc[mt][nt][r] * f;
                unsigned short h, l; split2(v, h, l);
                size_t o = (size_t)row * Hn + col;
                goh[o] = h; gol[o] = l;
                float uv = u[(size_t)row * NW + col];
                float a1 = 2.f * uv * v;
                split2(a1, h, l);
                a1h[o] = h; a1l[o] = l;
            }
        }
    }
}

// ---------------- gxslab[z] += A1@WqT + A2@WlT ; 64x64 tile, z-owned slab, no atomics ----------------

__global__ __launch_bounds__(256) void bwd_x_mfma(
    const unsigned short* __restrict__ a1h, const unsigned short* __restrict__ a1l,
    const unsigned short* __restrict__ a2h, const unsigned short* __restrict__ a2l,
    const unsigned short* __restrict__ WqTh, const unsigned short* __restrict__ WqTl,
    const unsigned short* __restrict__ WlTh, const unsigned short* __restrict__ WlTl,
    float* __restrict__ gxs)     // 2 slabs of [Bn][Dn]
{
    __shared__ __align__(16) char smem[32768];
    unsigned short* A1h = (unsigned short*)smem;            // [64][32] each
    unsigned short* A1l = (unsigned short*)(smem + 4096);
    unsigned short* A2h = (unsigned short*)(smem + 8192);
    unsigned short* A2l = (unsigned short*)(smem + 12288);
    unsigned short* Bqh = (unsigned short*)(smem + 16384);
    unsigned short* Bql = (unsigned short*)(smem + 20480);
    unsigned short* Blh = (unsigned short*)(smem + 24576);
    unsigned short* Bll = (unsigned short*)(smem + 28672);

    const int tid = threadIdx.x;
    const int w = tid >> 6, lane = tid & 63;
    const int lq = lane >> 4, lc = lane & 15;
    const int wm = (w & 1) * 32, wn = (w >> 1) * 32;
    const int row0 = blockIdx.x * 64, col0 = blockIdx.y * 64;
    const int kb = blockIdx.z * 256;
    float* gx = gxs + (size_t)blockIdx.z * Bn * Dn;
    const int str = tid >> 2, stk = (tid & 3) * 8;

    f32x4 acc[2][2];
#pragma unroll
    for (int i = 0; i < 2; ++i)
#pragma unroll
        for (int j = 0; j < 2; ++j)
#pragma unroll
            for (int r = 0; r < 4; ++r) acc[i][j][r] = 0.f;

    for (int k0 = kb; k0 < kb + 256; k0 += 32) {
        __syncthreads();
        {
            size_t ga_ = (size_t)(row0 + str) * Hn + k0 + stk;
            size_t gb = (size_t)(col0 + str) * Hn + k0 + stk;
            int lo_ = str * 32 + stk;
            gload16(a1h + ga_, A1h + lo_);
            gload16(a1l + ga_, A1l + lo_);
            gload16(a2h + ga_, A2h + lo_);
            gload16(a2l + ga_, A2l + lo_);
            gload16(WqTh + gb, Bqh + lo_);
            gload16(WqTl + gb, Bql + lo_);
            gload16(WlTh + gb, Blh + lo_);
            gload16(WlTl + gb, Bll + lo_);
        }
        __syncthreads();
        short8 f1h[2], f1l[2], f2h[2], f2l[2];
#pragma unroll
        for (int mt = 0; mt < 2; ++mt) {
            int ao = (wm + mt * 16 + lc) * 32 + lq * 8;
            f1h[mt] = *(const short8*)(A1h + ao);
            f1l[mt] = *(const short8*)(A1l + ao);
            f2h[mt] = *(const short8*)(A2h + ao);
            f2l[mt] = *(const short8*)(A2l + ao);
        }
#pragma unroll
        for (int nt = 0; nt < 2; ++nt) {
            int bo = (wn + nt * 16 + lc) * 32 + lq * 8;
            short8 qh = *(const short8*)(Bqh + bo);
            short8 ql_ = *(const short8*)(Bql + bo);
            short8 lh = *(const short8*)(Blh + bo);
            short8 ll_ = *(const short8*)(Bll + bo);
#pragma unroll
            for (int mt = 0; mt < 2; ++mt) {
                MFMA(acc[mt][nt], f1h[mt], qh);
                MFMA(acc[mt][nt], f1h[mt], ql_);
                MFMA(acc[mt][nt], f1l[mt], qh);
                MFMA(acc[mt][nt], f2h[mt], lh);
                MFMA(acc[mt][nt], f2h[mt], ll_);
                MFMA(acc[mt][nt], f2l[mt], lh);
            }
        }
    }

#pragma unroll
    for (int nt = 0; nt < 2; ++nt) {
        const int col = col0 + wn + nt * 16 + lc;
#pragma unroll
        for (int mt = 0; mt < 2; ++mt) {
            const int rowb = row0 + wm + mt * 16;
#pragma unroll
            for (int r = 0; r < 4; ++r) {
                size_t o = (size_t)(rowb + lq * 4 + r) * Dn + col;
                gx[o] += acc[mt][nt][r];
            }
        }
    }
}

// ---------------- small kernels ----------------

__global__ __launch_bounds__(256) void zero_buf(float* __restrict__ p, int n4) {
    int i = blockIdx.x * 256 + threadIdx.x;
    if (i < n4) ((float4*)p)[i] = make_float4(0.f, 0.f, 0.f, 0.f);
}

__global__ __launch_bounds__(256) void ga_init(
    const float* __restrict__ wz_out, const unsigned short* __restrict__ mask9,
    const float* __restrict__ u9,     // uall + 9*Hn, ld NW
    unsigned short* __restrict__ gh, unsigned short* __restrict__ gl,
    unsigned short* __restrict__ a1h, unsigned short* __restrict__ a1l)
{
    int i = blockIdx.x * 256 + threadIdx.x;
    int e = i << 2;
    int b = e >> 9, h = e & 511;
    unsigned short wbits = mask9[(size_t)b * 32 + (h >> 4)];
    float4 wv = *(const float4*)(wz_out + h);
    float4 uv = *(const float4*)(u9 + (size_t)b * NW + h);
    int sh = h & 15;
    ushort4 oh, ol, th, tl;
    float f;
    f = wv.x * (((wbits >> (sh + 0)) & 1) ? 1.f : NS); split2(f, oh.x, ol.x); split2(2.f * uv.x * f, th.x, tl.x);
    f = wv.y * (((wbits >> (sh + 1)) & 1) ? 1.f : NS); split2(f, oh.y, ol.y); split2(2.f * uv.y * f, th.y, tl.y);
    f = wv.z * (((wbits >> (sh + 2)) & 1) ? 1.f : NS); split2(f, oh.z, ol.z); split2(2.f * uv.z * f, th.z, tl.z);
    f = wv.w * (((wbits >> (sh + 3)) & 1) ? 1.f : NS); split2(f, oh.w, ol.w); split2(2.f * uv.w * f, th.w, tl.w);
    *(ushort4*)(gh + e) = oh;
    *(ushort4*)(gl + e) = ol;
    *(ushort4*)(a1h + e) = th;
    *(ushort4*)(a1l + e) = tl;
}

__global__ __launch_bounds__(256) void rowdot_kernel(
    const float* __restrict__ x, const float* __restrict__ wq_out, float* __restrict__ s) {
    const int b = blockIdx.x * 4 + (threadIdx.x >> 6);
    const int lane = threadIdx.x & 63;
    float v = x[(size_t)b * Dn + lane] * wq_out[lane] +
              x[(size_t)b * Dn + 64 + lane] * wq_out[64 + lane];
#pragma unroll
    for (int off = 32; off > 0; off >>= 1) v += __shfl_down(v, off, 64);
    if (lane == 0) s[b] = v;
}

__global__ __launch_bounds__(256) void final_kernel(
    float* __restrict__ out, const float* __restrict__ gxs,
    const float* __restrict__ x, const float* __restrict__ s,
    const float* __restrict__ wq_out, const float* __restrict__ wl_out) {
    const int i = blockIdx.x * 256 + threadIdx.x;
    const int base = i << 2;
    const int b = base >> 7;
    const int d = base & (Dn - 1);
    float4 g0 = *(const float4*)(gxs + base);
    float4 g1 = *(const float4*)(gxs + (size_t)Bn * Dn + base);
    float4 xv = *(const float4*)(x + base);
    float4 wq = *(const float4*)(wq_out + d);
    float4 wl = *(const float4*)(wl_out + d);
    const float sb = s[b];
    float4 o;
    o.x = 0.5f * (g0.x + g1.x) + sb * wq.x + 0.5f * wl.x + 0.5f * xv.x;
    o.y = 0.5f * (g0.y + g1.y) + sb * wq.y + 0.5f * wl.y + 0.5f * xv.y;
    o.z = 0.5f * (g0.z + g1.z) + sb * wq.z + 0.5f * wl.z + 0.5f * xv.z;
    o.w = 0.5f * (g0.w + g1.w) + sb * wq.w + 0.5f * wl.w + 0.5f * xv.w;
    *(float4*)(out + base) = o;
}

// ---------------- launcher ----------------

extern "C" void kernel_launch(void* const* d_in, const int* in_sizes, int n_in,
                              void* d_out, int out_size, void* d_ws, size_t ws_size,
                              hipStream_t stream) {
    (void)in_sizes; (void)n_in; (void)out_size; (void)ws_size;
    const float* x      = (const float*)d_in[0];
    const float* Wq     = (const float*)d_in[1];
    const float* Wl     = (const float*)d_in[2];
    const float* bl     = (const float*)d_in[3];
    const float* Wz     = (const float*)d_in[4];
    const float* wz_out = (const float*)d_in[5];
    const float* wq_out = (const float*)d_in[6];
    const float* wl_out = (const float*)d_in[7];
    float* out = (float*)d_out;

    char* p = (char*)d_ws;
    #define CARVE(name, bytes) unsigned short* name = (unsigned short*)p; p += (((size_t)(bytes)) + 255) & ~(size_t)255;
    CARVE(xh,  (size_t)Bn*Dn*2)  CARVE(xl,  (size_t)Bn*Dn*2)
    CARVE(Wqh, (size_t)Ln*Hn*Dn*2) CARVE(Wql, (size_t)Ln*Hn*Dn*2)
    CARVE(Wlh, (size_t)Ln*Hn*Dn*2) CARVE(Wll, (size_t)Ln*Hn*Dn*2)
    CARVE(WqTh,(size_t)Ln*Hn*Dn*2) CARVE(WqTl,(size_t)Ln*Hn*Dn*2)
    CARVE(WlTh,(size_t)Ln*Hn*Dn*2) CARVE(WlTl,(size_t)Ln*Hn*Dn*2)
    CARVE(Wzh, (size_t)(Ln-1)*Hn*Hn*2) CARVE(Wzl, (size_t)(Ln-1)*Hn*Hn*2)
    CARVE(WzTh,(size_t)(Ln-1)*Hn*Hn*2) CARVE(WzTl,(size_t)(Ln-1)*Hn*Hn*2)
    CARVE(zAh, (size_t)Bn*Hn*2) CARVE(zAl, (size_t)Bn*Hn*2)
    CARVE(zBh, (size_t)Bn*Hn*2) CARVE(zBl, (size_t)Bn*Hn*2)
    CARVE(a1h, (size_t)Bn*Hn*2) CARVE(a1l, (size_t)Bn*Hn*2)
    CARVE(mask16, (size_t)Ln*Bn*32*2)
    float* s = (float*)p; p += (size_t)Bn*4 + 256;
    float* gxs = (float*)p; p += (size_t)2*Bn*Dn*4;   // 2 fp32 slabs, 8.4 MB
    float* uall = (float*)p; p += (size_t)Bn*NW*4;    // 167.8 MB; total ~265.4 MB < 268.4 MB
    #undef CARVE

    split_flat<<<(Bn*Dn/4 + 255)/256, 256, 0, stream>>>(x, xh, xl, Bn*Dn/4);
    split_flat<<<(Ln*Hn*Dn/4 + 255)/256, 256, 0, stream>>>(Wq, Wqh, Wql, Ln*Hn*Dn/4);
    split_flat<<<(Ln*Hn*Dn/4 + 255)/256, 256, 0, stream>>>(Wl, Wlh, Wll, Ln*Hn*Dn/4);
    split_flat<<<((Ln-1)*Hn*Hn/4 + 255)/256, 256, 0, stream>>>(Wz, Wzh, Wzl, (Ln-1)*Hn*Hn/4);
    transpose_split<<<dim3(Hn/32, Dn/32, Ln), 256, 0, stream>>>(Wq, WqTh, WqTl, Hn, Dn);
    transpose_split<<<dim3(Hn/32, Dn/32, Ln), 256, 0, stream>>>(Wl, WlTh, WlTl, Hn, Dn);
    transpose_split<<<dim3(Hn/32, Hn/32, Ln-1), 256, 0, stream>>>(Wz, WzTh, WzTl, Hn, Hn);

    rowdot_kernel<<<Bn/4, 256, 0, stream>>>(x, wq_out, s);
    zero_buf<<<(2*Bn*Dn/4 + 255)/256, 256, 0, stream>>>(gxs, 2*Bn*Dn/4);

    gemm_uall<<<dim3(Bn/128, NW/128), 256, 0, stream>>>(xh, xl, Wqh, Wql, uall);

    const dim3 gF(Bn/128, Hn/64);  // 64 x 8

    fwd_mfma<<<gF, 256, 0, stream>>>(xh, xl, nullptr, nullptr, nullptr, nullptr,
        Wlh, Wll, bl, uall, zAh, zAl, mask16, 0);
    for (int l = 1; l < Ln; ++l) {
        const unsigned short* zh  = (l & 1) ? zAh : zBh;
        const unsigned short* zl_ = (l & 1) ? zAl : zBl;
        unsigned short* oh  = (l & 1) ? zBh : zAh;
        unsigned short* ol_ = (l & 1) ? zBl : zAl;
        fwd_mfma<<<gF, 256, 0, stream>>>(xh, xl, zh, zl_,
            Wzh + (size_t)(l-1)*Hn*Hn, Wzl + (size_t)(l-1)*Hn*Hn,
            Wlh + (size_t)l*Hn*Dn, Wll + (size_t)l*Hn*Dn,
            bl + (size_t)l*Hn, uall + (size_t)l*Hn,
            oh, ol_, mask16 + (size_t)l*Bn*32, 1);
    }

    ga_init<<<(Bn*Hn/4)/256, 256, 0, stream>>>(wz_out, mask16 + (size_t)9*Bn*32,
        uall + (size_t)9*Hn, zAh, zAl, a1h, a1l);

    for (int l = Ln - 1; l >= 0; --l) {
        int sidx = (Ln - 1 - l) & 1;
        const unsigned short* gh_ = sidx ? zBh : zAh;
        const unsigned short* gl_ = sidx ? zBl : zAl;
        bwd_x_mfma<<<dim3(Bn/64, Dn/64, 2), 256, 0, stream>>>(
            a1h, a1l, gh_, gl_,
            WqTh + (size_t)l*Dn*Hn, WqTl + (size_t)l*Dn*Hn,
            WlTh + (size_t)l*Dn*Hn, WlTl + (size_t)l*Dn*Hn, gxs);
        if (l > 0) {
            unsigned short* oh  = sidx ? zAh : zBh;
            unsigned short* ol_ = sidx ? zAl : zBl;
            bwd_g_mfma<<<gF, 256, 0, stream>>>(gh_, gl_,
                WzTh + (size_t)(l-1)*Hn*Hn, WzTl + (size_t)(l-1)*Hn*Hn,
                mask16 + (size_t)(l-1)*Bn*32,
                uall + (size_t)(l-1)*Hn,
                oh, ol_, a1h, a1l);
        }
    }

    final_kernel<<<(Bn*Dn/4)/256, 256, 0, stream>>>(out, gxs, x, s, wq_out, wl_out);
}

// Round 6
// 998.967 us; speedup vs baseline: 1.1242x; 1.0497x over previous
//
#include <hip/hip_runtime.h>

// ICNN forward-of-gradient: out = 0.5*d(scalar)/dx + 0.5*x
// R6: serial-chain kernels (fwd, bwd_g) moved to 64x64 tiles / 16KB LDS ->
//     grid 1024 (4 blocks/CU) to attack the latency-bound 8% MfmaUtil seen in R5.
//     uall / bwd_x / prep unchanged.

#define Bn 8192
#define Dn 128
#define Hn 512
#define Ln 10
#define NW (Ln * Hn)   // 5120

constexpr float NS = 0.2f;

typedef __attribute__((ext_vector_type(8))) short short8;
typedef __attribute__((ext_vector_type(4))) float f32x4;

typedef const __attribute__((address_space(1))) void GV;
typedef __attribute__((address_space(3))) void LV;

__device__ __forceinline__ void gload16(const void* g, void* l) {
    __builtin_amdgcn_global_load_lds((GV*)g, (LV*)l, 16, 0, 0);
}

#define MFMA(acc, a, b) acc = __builtin_amdgcn_mfma_f32_16x16x32_bf16(a, b, acc, 0, 0, 0)

__device__ __forceinline__ unsigned short bf16_rne(float v) {
    unsigned u = __float_as_uint(v);
    u += 0x7FFFu + ((u >> 16) & 1u);
    return (unsigned short)(u >> 16);
}
__device__ __forceinline__ float bf2f(unsigned short h) {
    return __uint_as_float(((unsigned)h) << 16);
}
__device__ __forceinline__ void split2(float v, unsigned short& h, unsigned short& l) {
    h = bf16_rne(v);
    l = bf16_rne(v - bf2f(h));
}

// ---------------- prep kernels ----------------

__global__ __launch_bounds__(256) void split_flat(const float* __restrict__ in,
        unsigned short* __restrict__ hi, unsigned short* __restrict__ lo, int n4) {
    int i = blockIdx.x * 256 + threadIdx.x;
    if (i >= n4) return;
    float4 v = ((const float4*)in)[i];
    ushort4 h, l;
    split2(v.x, h.x, l.x);
    split2(v.y, h.y, l.y);
    split2(v.z, h.z, l.z);
    split2(v.w, h.w, l.w);
    ((ushort4*)hi)[i] = h;
    ((ushort4*)lo)[i] = l;
}

__global__ __launch_bounds__(256) void transpose_split(const float* __restrict__ in,
        unsigned short* __restrict__ hi, unsigned short* __restrict__ lo, int R, int C) {
    __shared__ float t[32][33];
    const size_t off = (size_t)blockIdx.z * R * C;
    const float* src = in + off;
    unsigned short* dh = hi + off;
    unsigned short* dl = lo + off;
    const int r0 = blockIdx.x * 32, c0 = blockIdx.y * 32;
    const int tr = threadIdx.x >> 5, tc = threadIdx.x & 31;
#pragma unroll
    for (int i = 0; i < 4; ++i)
        t[tr + 8 * i][tc] = src[(size_t)(r0 + tr + 8 * i) * C + c0 + tc];
    __syncthreads();
#pragma unroll
    for (int i = 0; i < 4; ++i) {
        float v = t[tc][tr + 8 * i];
        unsigned short h, l; split2(v, h, l);
        size_t o = (size_t)(c0 + tr + 8 * i) * R + r0 + tc;
        dh[o] = h; dl[o] = l;
    }
}

// ---------------- u_all = x @ WqAll^T : [8192 x 5120] fp32, 128x128 tiles ----------------

__global__ __launch_bounds__(256) void gemm_uall(
    const unsigned short* __restrict__ xh, const unsigned short* __restrict__ xl,
    const unsigned short* __restrict__ Wh, const unsigned short* __restrict__ Wv,
    float* __restrict__ u)
{
    __shared__ __align__(16) char smem[32768];
    unsigned short* Ah = (unsigned short*)smem;            // [128][32]
    unsigned short* Al = (unsigned short*)(smem + 8192);
    unsigned short* Bh = (unsigned short*)(smem + 16384);  // [128][32]
    unsigned short* Bl = (unsigned short*)(smem + 24576);

    const int tid = threadIdx.x;
    const int w = tid >> 6, lane = tid & 63;
    const int lq = lane >> 4, lc = lane & 15;
    const int wm = (w & 1) * 64, wn = (w >> 1) * 64;
    const int row0 = blockIdx.x * 128, col0 = blockIdx.y * 128;
    const int sr = lane >> 2, sk = (lane & 3) * 8;

    f32x4 acc[4][4];
#pragma unroll
    for (int i = 0; i < 4; ++i)
#pragma unroll
        for (int j = 0; j < 4; ++j)
#pragma unroll
            for (int r = 0; r < 4; ++r) acc[i][j][r] = 0.f;

    for (int k0 = 0; k0 < Dn; k0 += 32) {
        __syncthreads();
        for (int c = w; c < 8; c += 4) {
            size_t ga_ = (size_t)(row0 + c * 16 + sr) * Dn + k0 + sk;
            gload16(xh + ga_, Ah + c * 512);
            gload16(xl + ga_, Al + c * 512);
            size_t gb = (size_t)(col0 + c * 16 + sr) * Dn + k0 + sk;
            gload16(Wh + gb, Bh + c * 512);
            gload16(Wv + gb, Bl + c * 512);
        }
        __syncthreads();
        short8 ah[4], al[4];
#pragma unroll
        for (int mt = 0; mt < 4; ++mt) {
            int ao = (wm + mt * 16 + lc) * 32 + lq * 8;
            ah[mt] = *(const short8*)(Ah + ao);
            al[mt] = *(const short8*)(Al + ao);
        }
#pragma unroll
        for (int nt = 0; nt < 4; ++nt) {
            int bo = (wn + nt * 16 + lc) * 32 + lq * 8;
            short8 bh = *(const short8*)(Bh + bo);
            short8 bv = *(const short8*)(Bl + bo);
#pragma unroll
            for (int mt = 0; mt < 4; ++mt) {
                MFMA(acc[mt][nt], ah[mt], bh);
                MFMA(acc[mt][nt], ah[mt], bv);
                MFMA(acc[mt][nt], al[mt], bh);
            }
        }
    }

#pragma unroll
    for (int nt = 0; nt < 4; ++nt) {
        const int col = col0 + wn + nt * 16 + lc;
#pragma unroll
        for (int mt = 0; mt < 4; ++mt) {
            const int rowb = row0 + wm + mt * 16;
#pragma unroll
            for (int r = 0; r < 4; ++r)
                u[(size_t)(rowb + lq * 4 + r) * NW + col] = acc[mt][nt][r];
        }
    }
}

// ---------------- fwd layer (64x64 tile): pre = zprev@Wz^T + u^2 + x@Wl^T + bl ----------------

__global__ __launch_bounds__(256) void fwd_mfma(
    const unsigned short* __restrict__ xh, const unsigned short* __restrict__ xl,
    const unsigned short* __restrict__ zph, const unsigned short* __restrict__ zpl,
    const unsigned short* __restrict__ Wzh, const unsigned short* __restrict__ Wzl,
    const unsigned short* __restrict__ Wlh, const unsigned short* __restrict__ Wll,
    const float* __restrict__ bl,
    const float* __restrict__ u,          // uall + l*Hn, ld = NW
    unsigned short* __restrict__ zoh, unsigned short* __restrict__ zol,
    unsigned short* __restrict__ mask16, int hasZ)
{
    __shared__ __align__(16) char smem[16384];
    unsigned short* Ah = (unsigned short*)smem;            // [64][32]
    unsigned short* Al = (unsigned short*)(smem + 4096);
    unsigned short* Bh = (unsigned short*)(smem + 8192);   // [64][32]
    unsigned short* Bl = (unsigned short*)(smem + 12288);

    const int tid = threadIdx.x;
    const int w = tid >> 6, lane = tid & 63;
    const int lq = lane >> 4, lc = lane & 15;
    const int wm = (w & 1) * 32, wn = (w >> 1) * 32;
    const int row0 = blockIdx.x * 64, col0 = blockIdx.y * 64;
    const int sr = lane >> 2, sk = (lane & 3) * 8;

    f32x4 acc[2][2];
#pragma unroll
    for (int i = 0; i < 2; ++i)
#pragma unroll
        for (int j = 0; j < 2; ++j)
#pragma unroll
            for (int r = 0; r < 4; ++r) acc[i][j][r] = 0.f;

    if (hasZ) {
        for (int k0 = 0; k0 < Hn; k0 += 32) {
            __syncthreads();
            {
                size_t ga_ = (size_t)(row0 + w * 16 + sr) * Hn + k0 + sk;
                size_t gb  = (size_t)(col0 + w * 16 + sr) * Hn + k0 + sk;
                gload16(zph + ga_, Ah + w * 512);
                gload16(zpl + ga_, Al + w * 512);
                gload16(Wzh + gb, Bh + w * 512);
                gload16(Wzl + gb, Bl + w * 512);
            }
            __syncthreads();
            short8 ah[2], al[2];
#pragma unroll
            for (int mt = 0; mt < 2; ++mt) {
                int ao = (wm + mt * 16 + lc) * 32 + lq * 8;
                ah[mt] = *(const short8*)(Ah + ao);
                al[mt] = *(const short8*)(Al + ao);
            }
#pragma unroll
            for (int nt = 0; nt < 2; ++nt) {
                int bo = (wn + nt * 16 + lc) * 32 + lq * 8;
                short8 bh = *(const short8*)(Bh + bo);
                short8 bv = *(const short8*)(Bl + bo);
#pragma unroll
                for (int mt = 0; mt < 2; ++mt) {
                    MFMA(acc[mt][nt], ah[mt], bh);
                    MFMA(acc[mt][nt], ah[mt], bv);
                    MFMA(acc[mt][nt], al[mt], bh);
                }
            }
        }
    }

    for (int k0 = 0; k0 < Dn; k0 += 32) {
        __syncthreads();
        {
            size_t ga_ = (size_t)(row0 + w * 16 + sr) * Dn + k0 + sk;
            size_t gb  = (size_t)(col0 + w * 16 + sr) * Dn + k0 + sk;
            gload16(xh + ga_, Ah + w * 512);
            gload16(xl + ga_, Al + w * 512);
            gload16(Wlh + gb, Bh + w * 512);
            gload16(Wll + gb, Bl + w * 512);
        }
        __syncthreads();
        short8 ah[2], al[2];
#pragma unroll
        for (int mt = 0; mt < 2; ++mt) {
            int ao = (wm + mt * 16 + lc) * 32 + lq * 8;
            ah[mt] = *(const short8*)(Ah + ao);
            al[mt] = *(const short8*)(Al + ao);
        }
#pragma unroll
        for (int nt = 0; nt < 2; ++nt) {
            int bo = (wn + nt * 16 + lc) * 32 + lq * 8;
            short8 bh = *(const short8*)(Bh + bo);
            short8 bv = *(const short8*)(Bl + bo);
#pragma unroll
            for (int mt = 0; mt < 2; ++mt) {
                MFMA(acc[mt][nt], ah[mt], bh);
                MFMA(acc[mt][nt], ah[mt], bv);
                MFMA(acc[mt][nt], al[mt], bh);
            }
        }
    }

#pragma unroll
    for (int nt = 0; nt < 2; ++nt) {
        const int colb = col0 + wn + nt * 16;
        const int col = colb + lc;
        const float blv = bl[col];
#pragma unroll
        for (int mt = 0; mt < 2; ++mt) {
            const int rowb = row0 + wm + mt * 16;
#pragma unroll
            for (int r = 0; r < 4; ++r) {
                const int row = rowb + lq * 4 + r;
                float uq = u[(size_t)row * NW + col];
                float pre = acc[mt][nt][r] + uq * uq + blv;
                bool m = pre >= 0.f;
                unsigned long long bal = __ballot(m);
                if (lc == 0) {
                    mask16[(size_t)row * 32 + (colb >> 4)] =
                        (unsigned short)((bal >> (lq * 16)) & 0xFFFFull);
                }
                float zv = m ? pre : NS * pre;
                unsigned short h, l; split2(zv, h, l);
                size_t o = (size_t)row * Hn + col;
                zoh[o] = h; zol[o] = l;
            }
        }
    }
}

// ---------------- bwd_g (64x64 tile): ga_{l-1} = (ga_l @ Wz) o mask' ; writes A1_{l-1} too ----------------

__global__ __launch_bounds__(256) void bwd_g_mfma(
    const unsigned short* __restrict__ gah, const unsigned short* __restrict__ gal,
    const unsigned short* __restrict__ WzTh, const unsigned short* __restrict__ WzTl,
    const unsigned short* __restrict__ maskprev,
    const float* __restrict__ u,          // uall + (l-1)*Hn, ld = NW
    unsigned short* __restrict__ goh, unsigned short* __restrict__ gol,
    unsigned short* __restrict__ a1h, unsigned short* __restrict__ a1l)
{
    __shared__ __align__(16) char smem[16384];
    unsigned short* Ah = (unsigned short*)smem;            // [64][32]
    unsigned short* Al = (unsigned short*)(smem + 4096);
    unsigned short* Bh = (unsigned short*)(smem + 8192);
    unsigned short* Bl = (unsigned short*)(smem + 12288);

    const int tid = threadIdx.x;
    const int w = tid >> 6, lane = tid & 63;
    const int lq = lane >> 4, lc = lane & 15;
    const int wm = (w & 1) * 32, wn = (w >> 1) * 32;
    const int row0 = blockIdx.x * 64, col0 = blockIdx.y * 64;
    const int sr = lane >> 2, sk = (lane & 3) * 8;

    f32x4 acc[2][2];
#pragma unroll
    for (int i = 0; i < 2; ++i)
#pragma unroll
        for (int j = 0; j < 2; ++j)
#pragma unroll
            for (int r = 0; r < 4; ++r) acc[i][j][r] = 0.f;

    for (int k0 = 0; k0 < Hn; k0 += 32) {
        __syncthreads();
        {
            size_t ga_ = (size_t)(row0 + w * 16 + sr) * Hn + k0 + sk;
            size_t gb  = (size_t)(col0 + w * 16 + sr) * Hn + k0 + sk;
            gload16(gah + ga_, Ah + w * 512);
            gload16(gal + ga_, Al + w * 512);
            gload16(WzTh + gb, Bh + w * 512);
            gload16(WzTl + gb, Bl + w * 512);
        }
        __syncthreads();
        short8 ah[2], al[2];
#pragma unroll
        for (int mt = 0; mt < 2; ++mt) {
            int ao = (wm + mt * 16 + lc) * 32 + lq * 8;
            ah[mt] = *(const short8*)(Ah + ao);
            al[mt] = *(const short8*)(Al + ao);
        }
#pragma unroll
        for (int nt = 0; nt < 2; ++nt) {
            int bo = (wn + nt * 16 + lc) * 32 + lq * 8;
            short8 bh = *(const short8*)(Bh + bo);
            short8 bv = *(const short8*)(Bl + bo);
#pragma unroll
            for (int mt = 0; mt < 2; ++mt) {
                MFMA(acc[mt][nt], ah[mt], bh);
                MFMA(acc[mt][nt], ah[mt], bv);
                MFMA(acc[mt][nt], al[mt], bh);
            }
        }
    }

#pragma unroll
    for (int nt = 0; nt < 2; ++nt) {
        const int colb = col0 + wn + nt * 16;
        const int col = colb + lc;
#pragma unroll
        for (int mt = 0; mt < 2; ++mt) {
            const int rowb = row0 + wm + mt * 16;
#pragma unroll
            for (int r = 0; r < 4; ++r) {
                int row = rowb + lq * 4 + r;
                unsigned short wbits = maskprev[(size_t)row * 32 + (colb >> 4)];
                float f = ((wbits >> lc) & 1) ? 1.f : NS;
                float v = acc[mt][nt][r] * f;
                unsigned short h, l; split2(v, h, l);
                size_t o = (size_t)row * Hn + col;
                goh[o] = h; gol[o] = l;
                float uv = u[(size_t)row * NW + col];
                float a1 = 2.f * uv * v;
                split2(a1, h, l);
                a1h[o] = h; a1l[o] = l;
            }
        }
    }
}

// ---------------- gxslab[z] += A1@WqT + A2@WlT ; 64x64 tile, z-owned slab ----------------

__global__ __launch_bounds__(256) void bwd_x_mfma(
    const unsigned short* __restrict__ a1h, const unsigned short* __restrict__ a1l,
    const unsigned short* __restrict__ a2h, const unsigned short* __restrict__ a2l,
    const unsigned short* __restrict__ WqTh, const unsigned short* __restrict__ WqTl,
    const unsigned short* __restrict__ WlTh, const unsigned short* __restrict__ WlTl,
    float* __restrict__ gxs)     // 2 slabs of [Bn][Dn]
{
    __shared__ __align__(16) char smem[32768];
    unsigned short* A1h = (unsigned short*)smem;            // [64][32] each
    unsigned short* A1l = (unsigned short*)(smem + 4096);
    unsigned short* A2h = (unsigned short*)(smem + 8192);
    unsigned short* A2l = (unsigned short*)(smem + 12288);
    unsigned short* Bqh = (unsigned short*)(smem + 16384);
    unsigned short* Bql = (unsigned short*)(smem + 20480);
    unsigned short* Blh = (unsigned short*)(smem + 24576);
    unsigned short* Bll = (unsigned short*)(smem + 28672);

    const int tid = threadIdx.x;
    const int w = tid >> 6, lane = tid & 63;
    const int lq = lane >> 4, lc = lane & 15;
    const int wm = (w & 1) * 32, wn = (w >> 1) * 32;
    const int row0 = blockIdx.x * 64, col0 = blockIdx.y * 64;
    const int kb = blockIdx.z * 256;
    float* gx = gxs + (size_t)blockIdx.z * Bn * Dn;
    const int str = tid >> 2, stk = (tid & 3) * 8;

    f32x4 acc[2][2];
#pragma unroll
    for (int i = 0; i < 2; ++i)
#pragma unroll
        for (int j = 0; j < 2; ++j)
#pragma unroll
            for (int r = 0; r < 4; ++r) acc[i][j][r] = 0.f;

    for (int k0 = kb; k0 < kb + 256; k0 += 32) {
        __syncthreads();
        {
            size_t ga_ = (size_t)(row0 + str) * Hn + k0 + stk;
            size_t gb = (size_t)(col0 + str) * Hn + k0 + stk;
            int lo_ = str * 32 + stk;
            gload16(a1h + ga_, A1h + lo_);
            gload16(a1l + ga_, A1l + lo_);
            gload16(a2h + ga_, A2h + lo_);
            gload16(a2l + ga_, A2l + lo_);
            gload16(WqTh + gb, Bqh + lo_);
            gload16(WqTl + gb, Bql + lo_);
            gload16(WlTh + gb, Blh + lo_);
            gload16(WlTl + gb, Bll + lo_);
        }
        __syncthreads();
        short8 f1h[2], f1l[2], f2h[2], f2l[2];
#pragma unroll
        for (int mt = 0; mt < 2; ++mt) {
            int ao = (wm + mt * 16 + lc) * 32 + lq * 8;
            f1h[mt] = *(const short8*)(A1h + ao);
            f1l[mt] = *(const short8*)(A1l + ao);
            f2h[mt] = *(const short8*)(A2h + ao);
            f2l[mt] = *(const short8*)(A2l + ao);
        }
#pragma unroll
        for (int nt = 0; nt < 2; ++nt) {
            int bo = (wn + nt * 16 + lc) * 32 + lq * 8;
            short8 qh = *(const short8*)(Bqh + bo);
            short8 ql_ = *(const short8*)(Bql + bo);
            short8 lh = *(const short8*)(Blh + bo);
            short8 ll_ = *(const short8*)(Bll + bo);
#pragma unroll
            for (int mt = 0; mt < 2; ++mt) {
                MFMA(acc[mt][nt], f1h[mt], qh);
                MFMA(acc[mt][nt], f1h[mt], ql_);
                MFMA(acc[mt][nt], f1l[mt], qh);
                MFMA(acc[mt][nt], f2h[mt], lh);
                MFMA(acc[mt][nt], f2h[mt], ll_);
                MFMA(acc[mt][nt], f2l[mt], lh);
            }
        }
    }

#pragma unroll
    for (int nt = 0; nt < 2; ++nt) {
        const int col = col0 + wn + nt * 16 + lc;
#pragma unroll
        for (int mt = 0; mt < 2; ++mt) {
            const int rowb = row0 + wm + mt * 16;
#pragma unroll
            for (int r = 0; r < 4; ++r) {
                size_t o = (size_t)(rowb + lq * 4 + r) * Dn + col;
                gx[o] += acc[mt][nt][r];
            }
        }
    }
}

// ---------------- small kernels ----------------

__global__ __launch_bounds__(256) void zero_buf(float* __restrict__ p, int n4) {
    int i = blockIdx.x * 256 + threadIdx.x;
    if (i < n4) ((float4*)p)[i] = make_float4(0.f, 0.f, 0.f, 0.f);
}

__global__ __launch_bounds__(256) void ga_init(
    const float* __restrict__ wz_out, const unsigned short* __restrict__ mask9,
    const float* __restrict__ u9,     // uall + 9*Hn, ld NW
    unsigned short* __restrict__ gh, unsigned short* __restrict__ gl,
    unsigned short* __restrict__ a1h, unsigned short* __restrict__ a1l)
{
    int i = blockIdx.x * 256 + threadIdx.x;
    int e = i << 2;
    int b = e >> 9, h = e & 511;
    unsigned short wbits = mask9[(size_t)b * 32 + (h >> 4)];
    float4 wv = *(const float4*)(wz_out + h);
    float4 uv = *(const float4*)(u9 + (size_t)b * NW + h);
    int sh = h & 15;
    ushort4 oh, ol, th, tl;
    float f;
    f = wv.x * (((wbits >> (sh + 0)) & 1) ? 1.f : NS); split2(f, oh.x, ol.x); split2(2.f * uv.x * f, th.x, tl.x);
    f = wv.y * (((wbits >> (sh + 1)) & 1) ? 1.f : NS); split2(f, oh.y, ol.y); split2(2.f * uv.y * f, th.y, tl.y);
    f = wv.z * (((wbits >> (sh + 2)) & 1) ? 1.f : NS); split2(f, oh.z, ol.z); split2(2.f * uv.z * f, th.z, tl.z);
    f = wv.w * (((wbits >> (sh + 3)) & 1) ? 1.f : NS); split2(f, oh.w, ol.w); split2(2.f * uv.w * f, th.w, tl.w);
    *(ushort4*)(gh + e) = oh;
    *(ushort4*)(gl + e) = ol;
    *(ushort4*)(a1h + e) = th;
    *(ushort4*)(a1l + e) = tl;
}

__global__ __launch_bounds__(256) void rowdot_kernel(
    const float* __restrict__ x, const float* __restrict__ wq_out, float* __restrict__ s) {
    const int b = blockIdx.x * 4 + (threadIdx.x >> 6);
    const int lane = threadIdx.x & 63;
    float v = x[(size_t)b * Dn + lane] * wq_out[lane] +
              x[(size_t)b * Dn + 64 + lane] * wq_out[64 + lane];
#pragma unroll
    for (int off = 32; off > 0; off >>= 1) v += __shfl_down(v, off, 64);
    if (lane == 0) s[b] = v;
}

__global__ __launch_bounds__(256) void final_kernel(
    float* __restrict__ out, const float* __restrict__ gxs,
    const float* __restrict__ x, const float* __restrict__ s,
    const float* __restrict__ wq_out, const float* __restrict__ wl_out) {
    const int i = blockIdx.x * 256 + threadIdx.x;
    const int base = i << 2;
    const int b = base >> 7;
    const int d = base & (Dn - 1);
    float4 g0 = *(const float4*)(gxs + base);
    float4 g1 = *(const float4*)(gxs + (size_t)Bn * Dn + base);
    float4 xv = *(const float4*)(x + base);
    float4 wq = *(const float4*)(wq_out + d);
    float4 wl = *(const float4*)(wl_out + d);
    const float sb = s[b];
    float4 o;
    o.x = 0.5f * (g0.x + g1.x) + sb * wq.x + 0.5f * wl.x + 0.5f * xv.x;
    o.y = 0.5f * (g0.y + g1.y) + sb * wq.y + 0.5f * wl.y + 0.5f * xv.y;
    o.z = 0.5f * (g0.z + g1.z) + sb * wq.z + 0.5f * wl.z + 0.5f * xv.z;
    o.w = 0.5f * (g0.w + g1.w) + sb * wq.w + 0.5f * wl.w + 0.5f * xv.w;
    *(float4*)(out + base) = o;
}

// ---------------- launcher ----------------

extern "C" void kernel_launch(void* const* d_in, const int* in_sizes, int n_in,
                              void* d_out, int out_size, void* d_ws, size_t ws_size,
                              hipStream_t stream) {
    (void)in_sizes; (void)n_in; (void)out_size; (void)ws_size;
    const float* x      = (const float*)d_in[0];
    const float* Wq     = (const float*)d_in[1];
    const float* Wl     = (const float*)d_in[2];
    const float* bl     = (const float*)d_in[3];
    const float* Wz     = (const float*)d_in[4];
    const float* wz_out = (const float*)d_in[5];
    const float* wq_out = (const float*)d_in[6];
    const float* wl_out = (const float*)d_in[7];
    float* out = (float*)d_out;

    char* p = (char*)d_ws;
    #define CARVE(name, bytes) unsigned short* name = (unsigned short*)p; p += (((size_t)(bytes)) + 255) & ~(size_t)255;
    CARVE(xh,  (size_t)Bn*Dn*2)  CARVE(xl,  (size_t)Bn*Dn*2)
    CARVE(Wqh, (size_t)Ln*Hn*Dn*2) CARVE(Wql, (size_t)Ln*Hn*Dn*2)
    CARVE(Wlh, (size_t)Ln*Hn*Dn*2) CARVE(Wll, (size_t)Ln*Hn*Dn*2)
    CARVE(WqTh,(size_t)Ln*Hn*Dn*2) CARVE(WqTl,(size_t)Ln*Hn*Dn*2)
    CARVE(WlTh,(size_t)Ln*Hn*Dn*2) CARVE(WlTl,(size_t)Ln*Hn*Dn*2)
    CARVE(Wzh, (size_t)(Ln-1)*Hn*Hn*2) CARVE(Wzl, (size_t)(Ln-1)*Hn*Hn*2)
    CARVE(WzTh,(size_t)(Ln-1)*Hn*Hn*2) CARVE(WzTl,(size_t)(Ln-1)*Hn*Hn*2)
    CARVE(zAh, (size_t)Bn*Hn*2) CARVE(zAl, (size_t)Bn*Hn*2)
    CARVE(zBh, (size_t)Bn*Hn*2) CARVE(zBl, (size_t)Bn*Hn*2)
    CARVE(a1h, (size_t)Bn*Hn*2) CARVE(a1l, (size_t)Bn*Hn*2)
    CARVE(mask16, (size_t)Ln*Bn*32*2)
    float* s = (float*)p; p += (size_t)Bn*4 + 256;
    float* gxs = (float*)p; p += (size_t)2*Bn*Dn*4;   // 2 fp32 slabs, 8.4 MB
    float* uall = (float*)p; p += (size_t)Bn*NW*4;    // 167.8 MB; total ~265.4 MB < 268.4 MB
    #undef CARVE

    split_flat<<<(Bn*Dn/4 + 255)/256, 256, 0, stream>>>(x, xh, xl, Bn*Dn/4);
    split_flat<<<(Ln*Hn*Dn/4 + 255)/256, 256, 0, stream>>>(Wq, Wqh, Wql, Ln*Hn*Dn/4);
    split_flat<<<(Ln*Hn*Dn/4 + 255)/256, 256, 0, stream>>>(Wl, Wlh, Wll, Ln*Hn*Dn/4);
    split_flat<<<((Ln-1)*Hn*Hn/4 + 255)/256, 256, 0, stream>>>(Wz, Wzh, Wzl, (Ln-1)*Hn*Hn/4);
    transpose_split<<<dim3(Hn/32, Dn/32, Ln), 256, 0, stream>>>(Wq, WqTh, WqTl, Hn, Dn);
    transpose_split<<<dim3(Hn/32, Dn/32, Ln), 256, 0, stream>>>(Wl, WlTh, WlTl, Hn, Dn);
    transpose_split<<<dim3(Hn/32, Hn/32, Ln-1), 256, 0, stream>>>(Wz, WzTh, WzTl, Hn, Hn);

    rowdot_kernel<<<Bn/4, 256, 0, stream>>>(x, wq_out, s);
    zero_buf<<<(2*Bn*Dn/4 + 255)/256, 256, 0, stream>>>(gxs, 2*Bn*Dn/4);

    gemm_uall<<<dim3(Bn/128, NW/128), 256, 0, stream>>>(xh, xl, Wqh, Wql, uall);

    const dim3 gF(Bn/64, Hn/64);  // 128 x 8 = 1024 blocks (4/CU)

    fwd_mfma<<<gF, 256, 0, stream>>>(xh, xl, nullptr, nullptr, nullptr, nullptr,
        Wlh, Wll, bl, uall, zAh, zAl, mask16, 0);
    for (int l = 1; l < Ln; ++l) {
        const unsigned short* zh  = (l & 1) ? zAh : zBh;
        const unsigned short* zl_ = (l & 1) ? zAl : zBl;
        unsigned short* oh  = (l & 1) ? zBh : zAh;
        unsigned short* ol_ = (l & 1) ? zBl : zAl;
        fwd_mfma<<<gF, 256, 0, stream>>>(xh, xl, zh, zl_,
            Wzh + (size_t)(l-1)*Hn*Hn, Wzl + (size_t)(l-1)*Hn*Hn,
            Wlh + (size_t)l*Hn*Dn, Wll + (size_t)l*Hn*Dn,
            bl + (size_t)l*Hn, uall + (size_t)l*Hn,
            oh, ol_, mask16 + (size_t)l*Bn*32, 1);
    }

    ga_init<<<(Bn*Hn/4)/256, 256, 0, stream>>>(wz_out, mask16 + (size_t)9*Bn*32,
        uall + (size_t)9*Hn, zAh, zAl, a1h, a1l);

    for (int l = Ln - 1; l >= 0; --l) {
        int sidx = (Ln - 1 - l) & 1;
        const unsigned short* gh_ = sidx ? zBh : zAh;
        const unsigned short* gl_ = sidx ? zBl : zAl;
        bwd_x_mfma<<<dim3(Bn/64, Dn/64, 2), 256, 0, stream>>>(
            a1h, a1l, gh_, gl_,
            WqTh + (size_t)l*Dn*Hn, WqTl + (size_t)l*Dn*Hn,
            WlTh + (size_t)l*Dn*Hn, WlTl + (size_t)l*Dn*Hn, gxs);
        if (l > 0) {
            unsigned short* oh  = sidx ? zAh : zBh;
            unsigned short* ol_ = sidx ? zAl : zBl;
            bwd_g_mfma<<<gF, 256, 0, stream>>>(gh_, gl_,
                WzTh + (size_t)(l-1)*Hn*Hn, WzTl + (size_t)(l-1)*Hn*Hn,
                mask16 + (size_t)(l-1)*Bn*32,
                uall + (size_t)(l-1)*Hn,
                oh, ol_, a1h, a1l);
        }
    }

    final_kernel<<<(Bn*Dn/4)/256, 256, 0, stream>>>(out, gxs, x, s, wq_out, wl_out);
}